// Round 7
// baseline (386.002 us; speedup 1.0000x reference)
//
#include <hip/hip_runtime.h>
#include <hip/hip_bf16.h>
#include <math.h>
#include <stdint.h>

// ---------------------------------------------------------------------------
// Attention_17231408791684: x->QKV (bias) -> RoPE -> sliding-window(128)
// causal attention w/ sinks -> O-proj (bias).  f32 in/out, bf16 compute.
// Round 14: weight-convert eliminated. Weights (wq/wk/wv/wo) are staged
// into LDS directly from f32 with in-register cvt (B operand only; A
// operand keeps the fast global_load_lds bf16 path). convert kernel
// shrinks to x-only (read 5x by qkv n-panels -> bf16 still pays there).
// Removes ~260MB of convert roundtrip traffic + a serial kernel launch
// at the cost of ~+65MB f32 weight fetch inside the (non-BW-bound) GEMMs.
// attn keeps r6's 32-row/2-block-per-CU form (r6: attn exonerated, -2us).
// ---------------------------------------------------------------------------

typedef __bf16 bf16x8 __attribute__((ext_vector_type(8)));
typedef float  f32x4  __attribute__((ext_vector_type(4)));
typedef uint32_t u32x4 __attribute__((ext_vector_type(4)));

#define MFMA_BF16(a,b,c) __builtin_amdgcn_mfma_f32_16x16x32_bf16((a),(b),(c),0,0,0)

// workspace element offsets (bf16 elements)
#define XB   0L
#define QB   32440320L
#define KB   40828928L
#define VB   41877504L

__device__ __forceinline__ void gld_lds16(const void* g, void* l) {
    __builtin_amdgcn_global_load_lds(
        (__attribute__((address_space(1))) void*)(g),
        (__attribute__((address_space(3))) void*)(l), 16, 0, 0);
}

__device__ __forceinline__ bf16x8 ld8f(const float* p) {
    f32x4 a = *(const f32x4*)p;
    f32x4 b = *(const f32x4*)(p + 4);
    bf16x8 r;
#pragma unroll
    for (int t = 0; t < 4; t++) { r[t] = (__bf16)a[t]; r[t + 4] = (__bf16)b[t]; }
    return r;
}

__device__ __forceinline__ uint32_t pack2(float a, float b) {
    __bf16 x = (__bf16)a, y = (__bf16)b;
    return (uint32_t)__builtin_bit_cast(unsigned short, x)
         | ((uint32_t)__builtin_bit_cast(unsigned short, y) << 16);
}

// ---------------------------------------------------------------------------
// f32 -> bf16 conversion of x only; 8 elems/thread, grid 2880x256 exact.
// ---------------------------------------------------------------------------
__global__ __launch_bounds__(256) void convert_kernel(
    const float* __restrict__ x, __bf16* __restrict__ dst)
{
    long e = ((long)blockIdx.x * 256 + threadIdx.x) * 8;
    *(bf16x8*)(dst + e) = ld8f(x + e);
}

// ---------------------------------------------------------------------------
// NT GEMM, BK=64, 128x128 tile, 256 thr (2x2 waves of 64x64).
// A: bf16, staged via global_load_lds (r2-proven path).
// W: f32, staged via ld8f reg-cvt + ds_write_b128 (B operand only).
// LDS [2][128][32]/operand. bias==nullptr -> none.
// ---------------------------------------------------------------------------
__device__ __forceinline__ void gemm_block64_fw(
    const __bf16* __restrict__ A, const float* __restrict__ W,
    const float* __restrict__ bias, __bf16* __restrict__ C,
    int N, int Ks, int kBeg, int kEnd, int m0, int n0,
    __bf16* As, __bf16* Bs)
{
    const int tid  = threadIdx.x;
    const int lane = tid & 63;
    const int wv   = tid >> 6;
    const int wm   = (wv >> 1) * 64;
    const int wn   = (wv & 1) * 64;
    const int quad = lane >> 4;
    const int c    = lane & 15;

    const int srow = tid >> 2;          // 0..63
    const int scol = (tid & 3) * 8;     // 0,8,16,24

    int br0 = n0 + srow;      if (br0 > N - 1) br0 = N - 1;
    int br1 = n0 + 64 + srow; if (br1 > N - 1) br1 = N - 1;
    const __bf16* pa0 = A + (size_t)(m0 + srow) * Ks + scol;
    const __bf16* pa1 = A + (size_t)(m0 + 64 + srow) * Ks + scol;
    const float*  pb0 = W + (size_t)br0 * Ks + scol;
    const float*  pb1 = W + (size_t)br1 * Ks + scol;

    f32x4 acc[4][4];
#pragma unroll
    for (int i = 0; i < 4; i++)
#pragma unroll
        for (int j = 0; j < 4; j++) acc[i][j] = (f32x4){0.f, 0.f, 0.f, 0.f};

    for (int kk = kBeg; kk < kEnd; kk += 64) {
        gld_lds16(pa0 + kk,      As + tid * 8);
        gld_lds16(pa1 + kk,      As + 2048 + tid * 8);
        gld_lds16(pa0 + kk + 32, As + 4096 + tid * 8);
        gld_lds16(pa1 + kk + 32, As + 6144 + tid * 8);
        bf16x8 b0 = ld8f(pb0 + kk);
        bf16x8 b1 = ld8f(pb1 + kk);
        bf16x8 b2 = ld8f(pb0 + kk + 32);
        bf16x8 b3 = ld8f(pb1 + kk + 32);
        *(bf16x8*)(Bs + tid * 8)        = b0;
        *(bf16x8*)(Bs + 2048 + tid * 8) = b1;
        *(bf16x8*)(Bs + 4096 + tid * 8) = b2;
        *(bf16x8*)(Bs + 6144 + tid * 8) = b3;
        __syncthreads();
        for (int kt = 0; kt < 2; kt++) {
            bf16x8 af[4], bfv[4];
#pragma unroll
            for (int i = 0; i < 4; i++)
                af[i] = *(const bf16x8*)&As[kt * 4096 + (wm + i * 16 + c) * 32 + quad * 8];
#pragma unroll
            for (int j = 0; j < 4; j++)
                bfv[j] = *(const bf16x8*)&Bs[kt * 4096 + (wn + j * 16 + c) * 32 + quad * 8];
#pragma unroll
            for (int i = 0; i < 4; i++)
#pragma unroll
                for (int j = 0; j < 4; j++)
                    acc[i][j] = MFMA_BF16(af[i], bfv[j], acc[i][j]);
        }
        __syncthreads();
    }

#pragma unroll
    for (int j = 0; j < 4; j++) {
        int col = n0 + wn + j * 16 + c;
        if (col >= N) continue;
        float bv = bias ? bias[col] : 0.0f;
#pragma unroll
        for (int i = 0; i < 4; i++) {
            int row = m0 + wm + i * 16 + quad * 4;
#pragma unroll
            for (int r = 0; r < 4; r++)
                C[(size_t)(row + r) * N + col] = (__bf16)(acc[i][j][r] + bv);
        }
    }
}

// Fused QKV, whole-K: grid (16,40); by<32 -> q, by<36 -> k, else v.
// XCD swizzle: 640 = 8 XCDs x 80. Weights read directly as f32.
__global__ __launch_bounds__(256, 3) void qkv_kernel(
    const __bf16* __restrict__ x,
    const float* __restrict__ wq, const float* __restrict__ bq,
    const float* __restrict__ wk, const float* __restrict__ bk,
    const float* __restrict__ wv, const float* __restrict__ bv,
    __bf16* __restrict__ qo, __bf16* __restrict__ ko, __bf16* __restrict__ vo)
{
    __shared__ __align__(16) __bf16 As[8192], Bs[8192];
    const int orig = blockIdx.y * 16 + blockIdx.x;
    const int wg   = (orig & 7) * 80 + (orig >> 3);
    const int bx   = wg & 15;
    const int by   = wg >> 4;
    const float *W; const float* bias; __bf16* C; int N, n0;
    if (by < 32)      { W = wq; bias = bq; C = qo; N = 4096; n0 = by * 128; }
    else if (by < 36) { W = wk; bias = bk; C = ko; N = 512;  n0 = (by - 32) * 128; }
    else              { W = wv; bias = bv; C = vo; N = 512;  n0 = (by - 36) * 128; }
    gemm_block64_fw(x, W, bias, C, N, 2880, 0, 2880, bx * 128, n0, As, Bs);
}

// O-proj split-K=2 partials: grid (16,23,2); per-z XCD swizzle 368 = 8x46.
// wo read directly as f32.
__global__ __launch_bounds__(256, 3) void oproj_kernel(
    const __bf16* __restrict__ a, const float* __restrict__ w,
    __bf16* __restrict__ p0, __bf16* __restrict__ p1)
{
    __shared__ __align__(16) __bf16 As[8192], Bs[8192];
    const int z = blockIdx.z;
    __bf16* C = z ? p1 : p0;
    const int orig = blockIdx.y * 16 + blockIdx.x;
    const int wg   = (orig & 7) * 46 + (orig >> 3);
    const int bx   = wg & 15;
    const int by   = wg >> 4;
    gemm_block64_fw(a, w, nullptr, C, 2880, 4096, z * 2048, (z + 1) * 2048,
                    bx * 128, by * 128, As, Bs);
}

// out[e] = p0[e] + p1[e] + bias[col]; 8 elems/thread, grid 2880x256 exact.
__global__ __launch_bounds__(256) void reduce_kernel(
    const __bf16* __restrict__ p0, const __bf16* __restrict__ p1,
    const float* __restrict__ bo, float* __restrict__ out)
{
    long e = ((long)blockIdx.x * 256 + threadIdx.x) * 8;
    int col = (int)(e % 2880L);          // 2880 % 8 == 0: no row crossing
    bf16x8 a = *(const bf16x8*)(p0 + e);
    bf16x8 b = *(const bf16x8*)(p1 + e);
    f32x4 o0, o1;
#pragma unroll
    for (int t = 0; t < 4; t++) {
        o0[t] = (float)a[t]     + (float)b[t]     + bo[col + t];
        o1[t] = (float)a[4 + t] + (float)b[4 + t] + bo[col + 4 + t];
    }
    *(f32x4*)(out + e)     = o0;
    *(f32x4*)(out + e + 4) = o1;
}

// ---------------------------------------------------------------------------
// Attention f-step, F in {0,1} compile-time (32-row q-tile). Static indices.
// acc9[jj] = S[key (F+jj)*16+quad*4+r][q = c] (swapped QK^T), softmax in
// lane-column group {c,c+16,c+32,c+48}, sink factor folded into P, P
// redistributed to PV A-frags via pack2 + shfl.
// ---------------------------------------------------------------------------
template<int F>
__device__ __forceinline__ void attn_f_step(
    const __bf16* __restrict__ Ks, const __bf16* __restrict__ Vt,
    __bf16* __restrict__ q, bf16x8 qf0, bf16x8 qf1,
    int i0, int h, int k0, float sk,
    int c, int quad, int laneA, int laneB, bool hiSel, int db)
{
    // ---- swapped QK^T
    f32x4 acc9[9];
#pragma unroll
    for (int jj = 0; jj < 9; jj++) acc9[jj] = (f32x4){0.f, 0.f, 0.f, 0.f};
    __builtin_amdgcn_s_setprio(1);
#pragma unroll
    for (int jj = 0; jj < 9; jj++) {
        const int j = F + jj;
        bf16x8 kf0 = *(const bf16x8*)&Ks[(j * 16 + c) * 72 + quad * 8];
        bf16x8 kf1 = *(const bf16x8*)&Ks[(j * 16 + c) * 72 + 32 + quad * 8];
        acc9[jj] = MFMA_BF16(kf0, qf0, acc9[jj]);
        acc9[jj] = MFMA_BF16(kf1, qf1, acc9[jj]);
    }
    __builtin_amdgcn_s_setprio(0);

    // ---- mask + row max (d = ig - jg; valid iff 0<=d<128 && jg>=0)
    const int jgb = k0 + F * 16 + quad * 4;
    float rmax = -3.0e4f;
#pragma unroll
    for (int jj = 0; jj < 9; jj++)
#pragma unroll
        for (int r = 0; r < 4; r++) {
            int d  = db  - jj * 16 - r;
            int jg = jgb + jj * 16 + r;
            bool ok = ((unsigned)d < 128u) && (jg >= 0);
            float vv = ok ? acc9[jj][r] : -3.0e4f;
            acc9[jj][r] = vv;
            rmax = fmaxf(rmax, vv);
        }
    rmax = fmaxf(rmax, __shfl_xor(rmax, 16));
    rmax = fmaxf(rmax, __shfl_xor(rmax, 32));

    float rs = 0.f;
#pragma unroll
    for (int jj = 0; jj < 9; jj++)
#pragma unroll
        for (int r = 0; r < 4; r++) {
            float e = __expf(acc9[jj][r] - rmax);
            acc9[jj][r] = e;
            rs += e;
        }
    rs += __shfl_xor(rs, 16);
    rs += __shfl_xor(rs, 32);

    // rowfac = sigmoid(lse - sink) / rowsum, folded into P
    float s   = fmaxf(rs, 1e-20f);
    float lse = rmax + __logf(s);
    float fac = 1.f / ((1.f + __expf(sk - lse)) * s);

    // ---- pack P*fac to bf16 pairs into static 20-word window
    uint32_t pk[20];
#pragma unroll
    for (int t = 0; t < 20; t++) pk[t] = 0;
#pragma unroll
    for (int jj = 0; jj < 9; jj++) {
        const int li = (F & 1) ? (2 * jj + 2) : (2 * jj);
        pk[li]     = pack2(acc9[jj][0] * fac, acc9[jj][1] * fac);
        pk[li + 1] = pack2(acc9[jj][2] * fac, acc9[jj][3] * fac);
    }

    // ---- PV: rebuild A-frags via shfl (within {c,c+16,c+32,c+48})
    f32x4 acc2[4];
#pragma unroll
    for (int jd = 0; jd < 4; jd++) acc2[jd] = (f32x4){0.f, 0.f, 0.f, 0.f};
#pragma unroll
    for (int kk = 0; kk < 5; kk++) {
        const int kt = (F >> 1) + kk;        // Vt chunk (F<2 -> kt = kk)
        uint32_t l0  = (uint32_t)__shfl((int)pk[4 * kk],     laneA);
        uint32_t h0  = (uint32_t)__shfl((int)pk[4 * kk + 1], laneA);
        uint32_t l0b = (uint32_t)__shfl((int)pk[4 * kk],     laneB);
        uint32_t h0b = (uint32_t)__shfl((int)pk[4 * kk + 1], laneB);
        uint32_t l1  = (uint32_t)__shfl((int)pk[4 * kk + 2], laneA);
        uint32_t h1  = (uint32_t)__shfl((int)pk[4 * kk + 3], laneA);
        uint32_t l1b = (uint32_t)__shfl((int)pk[4 * kk + 2], laneB);
        uint32_t h1b = (uint32_t)__shfl((int)pk[4 * kk + 3], laneB);
        u32x4 wvv = { hiSel ? l1  : l0,  hiSel ? h1  : h0,
                      hiSel ? l1b : l0b, hiSel ? h1b : h0b };
        bf16x8 pa = __builtin_bit_cast(bf16x8, wvv);
        __builtin_amdgcn_s_setprio(1);
#pragma unroll
        for (int jd = 0; jd < 4; jd++) {
            bf16x8 bv = *(const bf16x8*)&Vt[(jd * 16 + c) * 168 + kt * 32 + quad * 8];
            acc2[jd] = MFMA_BF16(pa, bv, acc2[jd]);
        }
        __builtin_amdgcn_s_setprio(0);
    }

    // ---- store O rows of this F (sink factor already folded into P)
#pragma unroll
    for (int jd = 0; jd < 4; jd++)
#pragma unroll
        for (int r = 0; r < 4; r++)
            q[(size_t)(i0 + F * 16 + quad * 4 + r) * 4096 + h * 64 + jd * 16 + c]
                = (__bf16)acc2[jd][r];
}

// ---------------------------------------------------------------------------
// Attention, fused RoPE, in-place on q. Grid (64 q-tiles of 32 rows, 8
// kv-heads), 512 threads = 8 waves; wave w = head kvh*8+w, all 32 rows.
// 512 blocks = 2/CU exactly -> 4 waves/SIMD.
// LDS: Ks[160][72] (2-way bank) + Vt[64][168] (2-way) = 44.5KB.
// ---------------------------------------------------------------------------
__global__ __launch_bounds__(512) void attn_kernel(
    __bf16* __restrict__ q, const __bf16* __restrict__ k,
    const __bf16* __restrict__ v, const float* __restrict__ sinks,
    const float* __restrict__ rope)
{
    __shared__ __align__(16) __bf16 Ks[160 * 72];
    __shared__ __align__(16) __bf16 Vt[64 * 168];

    const int tid = threadIdx.x, lane = tid & 63, w = tid >> 6;
    const int quad = lane >> 4, c = lane & 15;
    const int i0  = blockIdx.x * 32;
    const int kvh = blockIdx.y;
    const int h   = kvh * 8 + w;
    const int k0  = i0 - 128;
    const float scale = 0.16832169878499658f;   // (0.1*ln32+1)/sqrt(64)

    // ---- stage K with rope: 160 rows x 64 dims, 640 units of 16 elems
#pragma unroll
    for (int it = 0; it < 2; it++) {
        int unit = it * 512 + tid;
        if (unit < 640) {
            int krow = unit >> 2;
            int kdg  = (unit & 3) * 8;
            int j = k0 + krow; if (j < 0) j = 0;
            const __bf16* gp = k + (size_t)j * 512 + kvh * 64 + kdg;
            bf16x8 x1 = *(const bf16x8*)(gp);
            bf16x8 x2 = *(const bf16x8*)(gp + 32);
            const float* rc = rope + (size_t)j * 128 + kdg;
            bf16x8 o1, o2;
#pragma unroll
            for (int t = 0; t < 8; t++) {
                float cc = rc[t], si = rc[64 + t];
                float a = (float)x1[t], b = (float)x2[t];
                o1[t] = (__bf16)(a * cc - b * si);
                o2[t] = (__bf16)(b * cc + a * si);
            }
            *(bf16x8*)&Ks[krow * 72 + kdg]      = o1;
            *(bf16x8*)&Ks[krow * 72 + kdg + 32] = o2;
        }
    }

    // ---- stage V transposed: Vt[d][s], s in [0,160)
    {
        const int vrow = tid & 63;
        const int d0   = (tid >> 6) * 8;
#pragma unroll
        for (int it = 0; it < 3; it++) {
            int s = it * 64 + vrow;
            if (s < 160) {
                int j = k0 + s; if (j < 0) j = 0;
                bf16x8 t = *(const bf16x8*)(v + (size_t)j * 512 + kvh * 64 + d0);
#pragma unroll
                for (int u = 0; u < 8; u++) Vt[(d0 + u) * 168 + s] = t[u];
            }
        }
    }

    // ---- Q fragments (B-operand layout: row=c), rope + scale folded in
    bf16x8 qf[2][2];
#pragma unroll
    for (int f = 0; f < 2; f++) {
        const int row = i0 + f * 16 + c;
        const __bf16* gp = q + (size_t)row * 4096 + h * 64 + quad * 8;
        bf16x8 x1 = *(const bf16x8*)(gp);
        bf16x8 x2 = *(const bf16x8*)(gp + 32);
        const float* rc = rope + (size_t)row * 128 + quad * 8;
        bf16x8 o1, o2;
#pragma unroll
        for (int t = 0; t < 8; t++) {
            float cc = rc[t] * scale, si = rc[64 + t] * scale;
            float a = (float)x1[t], b = (float)x2[t];
            o1[t] = (__bf16)(a * cc - b * si);
            o2[t] = (__bf16)(b * cc + a * si);
        }
        qf[f][0] = o1; qf[f][1] = o2;
    }

    __syncthreads();

    const float sk   = sinks[h];
    const int laneA  = ((quad & 1) << 5) + c;   // owner quad (quad&1)*2
    const int laneB  = laneA + 16;              // owner quad (quad&1)*2+1
    const bool hiSel = (quad >> 1) != 0;        // needs j = 2kt+1
    const int db     = 128 + c - quad * 4;      // ig - jg, jj/r part removed

    attn_f_step<0>(Ks, Vt, q, qf[0][0], qf[0][1], i0, h, k0, sk, c, quad, laneA, laneB, hiSel, db);
    attn_f_step<1>(Ks, Vt, q, qf[1][0], qf[1][1], i0, h, k0, sk, c, quad, laneA, laneB, hiSel, db);
}

// ---------------------------------------------------------------------------
extern "C" void kernel_launch(void* const* d_in, const int* in_sizes, int n_in,
                              void* d_out, int out_size, void* d_ws, size_t ws_size,
                              hipStream_t stream) {
    const float* x    = (const float*)d_in[0];
    const float* rope = (const float*)d_in[1];
    const float* wq   = (const float*)d_in[2];
    const float* bq   = (const float*)d_in[3];
    const float* wk   = (const float*)d_in[4];
    const float* bk   = (const float*)d_in[5];
    const float* wv   = (const float*)d_in[6];
    const float* bv   = (const float*)d_in[7];
    const float* wo   = (const float*)d_in[8];
    const float* bo   = (const float*)d_in[9];
    const float* sk   = (const float*)d_in[10];
    float* out = (float*)d_out;

    __bf16* wsb = (__bf16*)d_ws;
    __bf16* xb  = wsb + XB;
    __bf16* qb  = wsb + QB;
    __bf16* kb  = wsb + KB;
    __bf16* vb  = wsb + VB;
    __bf16* po0 = wsb + 5898240L;      // oproj partials overlay dead region
    __bf16* po1 = wsb + 11796480L;

    convert_kernel<<<2880, 256, 0, stream>>>(x, xb);
    qkv_kernel<<<dim3(16, 40), 256, 0, stream>>>(xb, wq, bq, wk, bk, wv, bv,
                                                 qb, kb, vb);
    attn_kernel<<<dim3(64, 8), 512, 0, stream>>>(qb, kb, vb, sk, rope);
    oproj_kernel<<<dim3(16, 23, 2), 256, 0, stream>>>(qb, wo, po0, po1);
    reduce_kernel<<<2880, 256, 0, stream>>>(po0, po1, bo, out);
}

// Round 8
// 330.584 us; speedup vs baseline: 1.1676x; 1.1676x over previous
//
#include <hip/hip_runtime.h>
#include <hip/hip_bf16.h>
#include <math.h>
#include <stdint.h>

// ---------------------------------------------------------------------------
// Attention_17231408791684: x->QKV (bias) -> RoPE -> sliding-window(128)
// causal attention w/ sinks -> O-proj (bias).  f32 in/out, bf16 compute.
// Round 15: consolidation revert to the r6-verified best (328.2us).
// r7's f32-weight staging regressed qkv 78->135us (reg-staging breaks
// global_load_lds latency hiding + doubles weight fetch) -- reverted.
// Final configuration: full convert (x+weights) -> bf16; qkv 128x128
// gemm_block64 + XCD swizzle (78.7us, 0-conflict, FETCH 73MB); attn
// 32-row q-tiles, 512 blocks = 2/CU, K/V staged once per kv-head group,
// swapped QK^T + in-register softmax/P-redistribution; oproj split-K=2
// 128x128 + XCD swizzle; reduce adds partials + bias.
// ---------------------------------------------------------------------------

typedef __bf16 bf16x8 __attribute__((ext_vector_type(8)));
typedef float  f32x4  __attribute__((ext_vector_type(4)));
typedef uint32_t u32x4 __attribute__((ext_vector_type(4)));

#define MFMA_BF16(a,b,c) __builtin_amdgcn_mfma_f32_16x16x32_bf16((a),(b),(c),0,0,0)

// workspace element offsets (bf16 elements)
#define XB   0L
#define WQB  5898240L
#define WKB  17694720L
#define WVB  19169280L
#define WOB  20643840L
#define QB   32440320L
#define KB   40828928L
#define VB   41877504L

__device__ __forceinline__ void gld_lds16(const void* g, void* l) {
    __builtin_amdgcn_global_load_lds(
        (__attribute__((address_space(1))) void*)(g),
        (__attribute__((address_space(3))) void*)(l), 16, 0, 0);
}

__device__ __forceinline__ bf16x8 ld8f(const float* p) {
    f32x4 a = *(const f32x4*)p;
    f32x4 b = *(const f32x4*)(p + 4);
    bf16x8 r;
#pragma unroll
    for (int t = 0; t < 4; t++) { r[t] = (__bf16)a[t]; r[t + 4] = (__bf16)b[t]; }
    return r;
}

__device__ __forceinline__ uint32_t pack2(float a, float b) {
    __bf16 x = (__bf16)a, y = (__bf16)b;
    return (uint32_t)__builtin_bit_cast(unsigned short, x)
         | ((uint32_t)__builtin_bit_cast(unsigned short, y) << 16);
}

// ---------------------------------------------------------------------------
// f32 -> bf16 conversion of {x, wq, wk, wv, wo}; 8 elems/thread, 15840x256.
// ---------------------------------------------------------------------------
__global__ __launch_bounds__(256) void convert_kernel(
    const float* __restrict__ x,  const float* __restrict__ wq,
    const float* __restrict__ wk, const float* __restrict__ wv,
    const float* __restrict__ wo, __bf16* __restrict__ dst)
{
    long e = ((long)blockIdx.x * 256 + threadIdx.x) * 8;
    const float* src; long off;
    if      (e <  WQB) { src = x;  off = e; }
    else if (e <  WKB) { src = wq; off = e - WQB; }
    else if (e <  WVB) { src = wk; off = e - WKB; }
    else if (e <  WOB) { src = wv; off = e - WVB; }
    else               { src = wo; off = e - WOB; }
    *(bf16x8*)(dst + e) = ld8f(src + off);
}

// ---------------------------------------------------------------------------
// NT GEMM, BK=64, k in [kBeg,kEnd). 128x128 tile, 256 thr (2x2 waves of
// 64x64). LDS [2][128][32]/operand. bias==nullptr -> none.  (r2-proven)
// ---------------------------------------------------------------------------
__device__ __forceinline__ void gemm_block64(
    const __bf16* __restrict__ A, const __bf16* __restrict__ W,
    const float* __restrict__ bias, __bf16* __restrict__ C,
    int N, int Ks, int kBeg, int kEnd, int m0, int n0,
    __bf16* As, __bf16* Bs)
{
    const int tid  = threadIdx.x;
    const int lane = tid & 63;
    const int wv   = tid >> 6;
    const int wm   = (wv >> 1) * 64;
    const int wn   = (wv & 1) * 64;
    const int quad = lane >> 4;
    const int c    = lane & 15;

    const int srow = tid >> 2;          // 0..63
    const int scol = (tid & 3) * 8;     // 0,8,16,24

    int br0 = n0 + srow;      if (br0 > N - 1) br0 = N - 1;
    int br1 = n0 + 64 + srow; if (br1 > N - 1) br1 = N - 1;
    const __bf16* pa0 = A + (size_t)(m0 + srow) * Ks + scol;
    const __bf16* pa1 = A + (size_t)(m0 + 64 + srow) * Ks + scol;
    const __bf16* pb0 = W + (size_t)br0 * Ks + scol;
    const __bf16* pb1 = W + (size_t)br1 * Ks + scol;

    f32x4 acc[4][4];
#pragma unroll
    for (int i = 0; i < 4; i++)
#pragma unroll
        for (int j = 0; j < 4; j++) acc[i][j] = (f32x4){0.f, 0.f, 0.f, 0.f};

    for (int kk = kBeg; kk < kEnd; kk += 64) {
        gld_lds16(pa0 + kk,      As + tid * 8);
        gld_lds16(pa1 + kk,      As + 2048 + tid * 8);
        gld_lds16(pa0 + kk + 32, As + 4096 + tid * 8);
        gld_lds16(pa1 + kk + 32, As + 6144 + tid * 8);
        gld_lds16(pb0 + kk,      Bs + tid * 8);
        gld_lds16(pb1 + kk,      Bs + 2048 + tid * 8);
        gld_lds16(pb0 + kk + 32, Bs + 4096 + tid * 8);
        gld_lds16(pb1 + kk + 32, Bs + 6144 + tid * 8);
        __syncthreads();
        for (int kt = 0; kt < 2; kt++) {
            bf16x8 af[4], bfv[4];
#pragma unroll
            for (int i = 0; i < 4; i++)
                af[i] = *(const bf16x8*)&As[kt * 4096 + (wm + i * 16 + c) * 32 + quad * 8];
#pragma unroll
            for (int j = 0; j < 4; j++)
                bfv[j] = *(const bf16x8*)&Bs[kt * 4096 + (wn + j * 16 + c) * 32 + quad * 8];
#pragma unroll
            for (int i = 0; i < 4; i++)
#pragma unroll
                for (int j = 0; j < 4; j++)
                    acc[i][j] = MFMA_BF16(af[i], bfv[j], acc[i][j]);
        }
        __syncthreads();
    }

#pragma unroll
    for (int j = 0; j < 4; j++) {
        int col = n0 + wn + j * 16 + c;
        if (col >= N) continue;
        float bv = bias ? bias[col] : 0.0f;
#pragma unroll
        for (int i = 0; i < 4; i++) {
            int row = m0 + wm + i * 16 + quad * 4;
#pragma unroll
            for (int r = 0; r < 4; r++)
                C[(size_t)(row + r) * N + col] = (__bf16)(acc[i][j][r] + bv);
        }
    }
}

// Fused QKV, whole-K: grid (16,40); by<32 -> q, by<36 -> k, else v.
// XCD swizzle: 640 = 8 XCDs x 80 (r2-proven: FETCH 121->73MB, 78.7us).
__global__ __launch_bounds__(256, 3) void qkv_kernel(
    const __bf16* __restrict__ x,
    const __bf16* __restrict__ wq, const float* __restrict__ bq,
    const __bf16* __restrict__ wk, const float* __restrict__ bk,
    const __bf16* __restrict__ wv, const float* __restrict__ bv,
    __bf16* __restrict__ qo, __bf16* __restrict__ ko, __bf16* __restrict__ vo)
{
    __shared__ __align__(16) __bf16 As[8192], Bs[8192];
    const int orig = blockIdx.y * 16 + blockIdx.x;
    const int wg   = (orig & 7) * 80 + (orig >> 3);
    const int bx   = wg & 15;
    const int by   = wg >> 4;
    const __bf16 *W; const float* bias; __bf16* C; int N, n0;
    if (by < 32)      { W = wq; bias = bq; C = qo; N = 4096; n0 = by * 128; }
    else if (by < 36) { W = wk; bias = bk; C = ko; N = 512;  n0 = (by - 32) * 128; }
    else              { W = wv; bias = bv; C = vo; N = 512;  n0 = (by - 36) * 128; }
    gemm_block64(x, W, bias, C, N, 2880, 0, 2880, bx * 128, n0, As, Bs);
}

// O-proj split-K=2 partials: grid (16,23,2); per-z XCD swizzle 368 = 8x46.
__global__ __launch_bounds__(256, 3) void oproj_kernel(
    const __bf16* __restrict__ a, const __bf16* __restrict__ w,
    __bf16* __restrict__ p0, __bf16* __restrict__ p1)
{
    __shared__ __align__(16) __bf16 As[8192], Bs[8192];
    const int z = blockIdx.z;
    __bf16* C = z ? p1 : p0;
    const int orig = blockIdx.y * 16 + blockIdx.x;
    const int wg   = (orig & 7) * 46 + (orig >> 3);
    const int bx   = wg & 15;
    const int by   = wg >> 4;
    gemm_block64(a, w, nullptr, C, 2880, 4096, z * 2048, (z + 1) * 2048,
                 bx * 128, by * 128, As, Bs);
}

// out[e] = p0[e] + p1[e] + bias[col]; 8 elems/thread, grid 2880x256 exact.
__global__ __launch_bounds__(256) void reduce_kernel(
    const __bf16* __restrict__ p0, const __bf16* __restrict__ p1,
    const float* __restrict__ bo, float* __restrict__ out)
{
    long e = ((long)blockIdx.x * 256 + threadIdx.x) * 8;
    int col = (int)(e % 2880L);          // 2880 % 8 == 0: no row crossing
    bf16x8 a = *(const bf16x8*)(p0 + e);
    bf16x8 b = *(const bf16x8*)(p1 + e);
    f32x4 o0, o1;
#pragma unroll
    for (int t = 0; t < 4; t++) {
        o0[t] = (float)a[t]     + (float)b[t]     + bo[col + t];
        o1[t] = (float)a[4 + t] + (float)b[4 + t] + bo[col + 4 + t];
    }
    *(f32x4*)(out + e)     = o0;
    *(f32x4*)(out + e + 4) = o1;
}

// ---------------------------------------------------------------------------
// Attention f-step, F in {0,1} compile-time (32-row q-tile). Static indices.
// acc9[jj] = S[key (F+jj)*16+quad*4+r][q = c] (swapped QK^T), softmax in
// lane-column group {c,c+16,c+32,c+48}, sink factor folded into P, P
// redistributed to PV A-frags via pack2 + shfl.  Mask term
// d = 128+c-quad*4 - jj*16 - r is F/i0-invariant (verified r1-r6).
// ---------------------------------------------------------------------------
template<int F>
__device__ __forceinline__ void attn_f_step(
    const __bf16* __restrict__ Ks, const __bf16* __restrict__ Vt,
    __bf16* __restrict__ q, bf16x8 qf0, bf16x8 qf1,
    int i0, int h, int k0, float sk,
    int c, int quad, int laneA, int laneB, bool hiSel, int db)
{
    // ---- swapped QK^T
    f32x4 acc9[9];
#pragma unroll
    for (int jj = 0; jj < 9; jj++) acc9[jj] = (f32x4){0.f, 0.f, 0.f, 0.f};
    __builtin_amdgcn_s_setprio(1);
#pragma unroll
    for (int jj = 0; jj < 9; jj++) {
        const int j = F + jj;
        bf16x8 kf0 = *(const bf16x8*)&Ks[(j * 16 + c) * 72 + quad * 8];
        bf16x8 kf1 = *(const bf16x8*)&Ks[(j * 16 + c) * 72 + 32 + quad * 8];
        acc9[jj] = MFMA_BF16(kf0, qf0, acc9[jj]);
        acc9[jj] = MFMA_BF16(kf1, qf1, acc9[jj]);
    }
    __builtin_amdgcn_s_setprio(0);

    // ---- mask + row max (d = ig - jg; valid iff 0<=d<128 && jg>=0)
    const int jgb = k0 + F * 16 + quad * 4;
    float rmax = -3.0e4f;
#pragma unroll
    for (int jj = 0; jj < 9; jj++)
#pragma unroll
        for (int r = 0; r < 4; r++) {
            int d  = db  - jj * 16 - r;
            int jg = jgb + jj * 16 + r;
            bool ok = ((unsigned)d < 128u) && (jg >= 0);
            float vv = ok ? acc9[jj][r] : -3.0e4f;
            acc9[jj][r] = vv;
            rmax = fmaxf(rmax, vv);
        }
    rmax = fmaxf(rmax, __shfl_xor(rmax, 16));
    rmax = fmaxf(rmax, __shfl_xor(rmax, 32));

    float rs = 0.f;
#pragma unroll
    for (int jj = 0; jj < 9; jj++)
#pragma unroll
        for (int r = 0; r < 4; r++) {
            float e = __expf(acc9[jj][r] - rmax);
            acc9[jj][r] = e;
            rs += e;
        }
    rs += __shfl_xor(rs, 16);
    rs += __shfl_xor(rs, 32);

    // rowfac = sigmoid(lse - sink) / rowsum, folded into P
    float s   = fmaxf(rs, 1e-20f);
    float lse = rmax + __logf(s);
    float fac = 1.f / ((1.f + __expf(sk - lse)) * s);

    // ---- pack P*fac to bf16 pairs into static 20-word window
    // global word 2j -> local (F even ? 2jj : 2jj+2); pads are masked zeros
    uint32_t pk[20];
#pragma unroll
    for (int t = 0; t < 20; t++) pk[t] = 0;
#pragma unroll
    for (int jj = 0; jj < 9; jj++) {
        const int li = (F & 1) ? (2 * jj + 2) : (2 * jj);
        pk[li]     = pack2(acc9[jj][0] * fac, acc9[jj][1] * fac);
        pk[li + 1] = pack2(acc9[jj][2] * fac, acc9[jj][3] * fac);
    }

    // ---- PV: rebuild A-frags via shfl (within {c,c+16,c+32,c+48})
    f32x4 acc2[4];
#pragma unroll
    for (int jd = 0; jd < 4; jd++) acc2[jd] = (f32x4){0.f, 0.f, 0.f, 0.f};
#pragma unroll
    for (int kk = 0; kk < 5; kk++) {
        const int kt = (F >> 1) + kk;        // Vt chunk (F<2 -> kt = kk)
        uint32_t l0  = (uint32_t)__shfl((int)pk[4 * kk],     laneA);
        uint32_t h0  = (uint32_t)__shfl((int)pk[4 * kk + 1], laneA);
        uint32_t l0b = (uint32_t)__shfl((int)pk[4 * kk],     laneB);
        uint32_t h0b = (uint32_t)__shfl((int)pk[4 * kk + 1], laneB);
        uint32_t l1  = (uint32_t)__shfl((int)pk[4 * kk + 2], laneA);
        uint32_t h1  = (uint32_t)__shfl((int)pk[4 * kk + 3], laneA);
        uint32_t l1b = (uint32_t)__shfl((int)pk[4 * kk + 2], laneB);
        uint32_t h1b = (uint32_t)__shfl((int)pk[4 * kk + 3], laneB);
        u32x4 wvv = { hiSel ? l1  : l0,  hiSel ? h1  : h0,
                      hiSel ? l1b : l0b, hiSel ? h1b : h0b };
        bf16x8 pa = __builtin_bit_cast(bf16x8, wvv);
        __builtin_amdgcn_s_setprio(1);
#pragma unroll
        for (int jd = 0; jd < 4; jd++) {
            bf16x8 bv = *(const bf16x8*)&Vt[(jd * 16 + c) * 168 + kt * 32 + quad * 8];
            acc2[jd] = MFMA_BF16(pa, bv, acc2[jd]);
        }
        __builtin_amdgcn_s_setprio(0);
    }

    // ---- store O rows of this F (sink factor already folded into P)
#pragma unroll
    for (int jd = 0; jd < 4; jd++)
#pragma unroll
        for (int r = 0; r < 4; r++)
            q[(size_t)(i0 + F * 16 + quad * 4 + r) * 4096 + h * 64 + jd * 16 + c]
                = (__bf16)acc2[jd][r];
}

// ---------------------------------------------------------------------------
// Attention, fused RoPE, in-place on q. Grid (64 q-tiles of 32 rows, 8
// kv-heads), 512 threads = 8 waves; wave w = head kvh*8+w, all 32 rows.
// 512 blocks = 2/CU exactly -> 4 waves/SIMD.
// K (rope'd, 160 rows) and V^T staged ONCE per block (shared by 8 heads).
// LDS: Ks[160][72] (2-way bank) + Vt[64][168] (2-way) = 44.5KB.
// ---------------------------------------------------------------------------
__global__ __launch_bounds__(512) void attn_kernel(
    __bf16* __restrict__ q, const __bf16* __restrict__ k,
    const __bf16* __restrict__ v, const float* __restrict__ sinks,
    const float* __restrict__ rope)
{
    __shared__ __align__(16) __bf16 Ks[160 * 72];
    __shared__ __align__(16) __bf16 Vt[64 * 168];

    const int tid = threadIdx.x, lane = tid & 63, w = tid >> 6;
    const int quad = lane >> 4, c = lane & 15;
    const int i0  = blockIdx.x * 32;
    const int kvh = blockIdx.y;
    const int h   = kvh * 8 + w;
    const int k0  = i0 - 128;
    const float scale = 0.16832169878499658f;   // (0.1*ln32+1)/sqrt(64)

    // ---- stage K with rope: 160 rows x 64 dims, 640 units of 16 elems
#pragma unroll
    for (int it = 0; it < 2; it++) {
        int unit = it * 512 + tid;
        if (unit < 640) {
            int krow = unit >> 2;
            int kdg  = (unit & 3) * 8;
            int j = k0 + krow; if (j < 0) j = 0;
            const __bf16* gp = k + (size_t)j * 512 + kvh * 64 + kdg;
            bf16x8 x1 = *(const bf16x8*)(gp);
            bf16x8 x2 = *(const bf16x8*)(gp + 32);
            const float* rc = rope + (size_t)j * 128 + kdg;
            bf16x8 o1, o2;
#pragma unroll
            for (int t = 0; t < 8; t++) {
                float cc = rc[t], si = rc[64 + t];
                float a = (float)x1[t], b = (float)x2[t];
                o1[t] = (__bf16)(a * cc - b * si);
                o2[t] = (__bf16)(b * cc + a * si);
            }
            *(bf16x8*)&Ks[krow * 72 + kdg]      = o1;
            *(bf16x8*)&Ks[krow * 72 + kdg + 32] = o2;
        }
    }

    // ---- stage V transposed: Vt[d][s], s in [0,160)
    {
        const int vrow = tid & 63;
        const int d0   = (tid >> 6) * 8;
#pragma unroll
        for (int it = 0; it < 3; it++) {
            int s = it * 64 + vrow;
            if (s < 160) {
                int j = k0 + s; if (j < 0) j = 0;
                bf16x8 t = *(const bf16x8*)(v + (size_t)j * 512 + kvh * 64 + d0);
#pragma unroll
                for (int u = 0; u < 8; u++) Vt[(d0 + u) * 168 + s] = t[u];
            }
        }
    }

    // ---- Q fragments (B-operand layout: row=c), rope + scale folded in
    bf16x8 qf[2][2];
#pragma unroll
    for (int f = 0; f < 2; f++) {
        const int row = i0 + f * 16 + c;
        const __bf16* gp = q + (size_t)row * 4096 + h * 64 + quad * 8;
        bf16x8 x1 = *(const bf16x8*)(gp);
        bf16x8 x2 = *(const bf16x8*)(gp + 32);
        const float* rc = rope + (size_t)row * 128 + quad * 8;
        bf16x8 o1, o2;
#pragma unroll
        for (int t = 0; t < 8; t++) {
            float cc = rc[t] * scale, si = rc[64 + t] * scale;
            float a = (float)x1[t], b = (float)x2[t];
            o1[t] = (__bf16)(a * cc - b * si);
            o2[t] = (__bf16)(b * cc + a * si);
        }
        qf[f][0] = o1; qf[f][1] = o2;
    }

    __syncthreads();

    const float sk   = sinks[h];
    const int laneA  = ((quad & 1) << 5) + c;   // owner quad (quad&1)*2
    const int laneB  = laneA + 16;              // owner quad (quad&1)*2+1
    const bool hiSel = (quad >> 1) != 0;        // needs j = 2kt+1
    const int db     = 128 + c - quad * 4;      // ig - jg, jj/r part removed

    attn_f_step<0>(Ks, Vt, q, qf[0][0], qf[0][1], i0, h, k0, sk, c, quad, laneA, laneB, hiSel, db);
    attn_f_step<1>(Ks, Vt, q, qf[1][0], qf[1][1], i0, h, k0, sk, c, quad, laneA, laneB, hiSel, db);
}

// ---------------------------------------------------------------------------
extern "C" void kernel_launch(void* const* d_in, const int* in_sizes, int n_in,
                              void* d_out, int out_size, void* d_ws, size_t ws_size,
                              hipStream_t stream) {
    const float* x    = (const float*)d_in[0];
    const float* rope = (const float*)d_in[1];
    const float* wq   = (const float*)d_in[2];
    const float* bq   = (const float*)d_in[3];
    const float* wk   = (const float*)d_in[4];
    const float* bk   = (const float*)d_in[5];
    const float* wv   = (const float*)d_in[6];
    const float* bv   = (const float*)d_in[7];
    const float* wo   = (const float*)d_in[8];
    const float* bo   = (const float*)d_in[9];
    const float* sk   = (const float*)d_in[10];
    float* out = (float*)d_out;

    __bf16* wsb = (__bf16*)d_ws;
    __bf16* xb  = wsb + XB;
    __bf16* wqb = wsb + WQB;
    __bf16* wkb = wsb + WKB;
    __bf16* wvb = wsb + WVB;
    __bf16* wob = wsb + WOB;
    __bf16* qb  = wsb + QB;
    __bf16* kb  = wsb + KB;
    __bf16* vb  = wsb + VB;
    __bf16* po0 = wsb + 0L;            // oproj partials overlay dead xb/wqb
    __bf16* po1 = wsb + 5898240L;

    convert_kernel<<<15840, 256, 0, stream>>>(x, wq, wk, wv, wo, xb);
    qkv_kernel<<<dim3(16, 40), 256, 0, stream>>>(xb, wqb, bq, wkb, bk, wvb, bv,
                                                 qb, kb, vb);
    attn_kernel<<<dim3(64, 8), 512, 0, stream>>>(qb, kb, vb, sk, rope);
    oproj_kernel<<<dim3(16, 23, 2), 256, 0, stream>>>(qb, wob, po0, po1);
    reduce_kernel<<<2880, 256, 0, stream>>>(po0, po1, bo, out);
}